// Round 1
// baseline (923.200 us; speedup 1.0000x reference)
//
#include <hip/hip_runtime.h>
#include <stdint.h>

#define NTAGS 256
#define BATCH 64
#define SEQ   512

// ---------------- wave (64-lane) reductions ----------------
__device__ __forceinline__ float wave_max(float v) {
#pragma unroll
  for (int o = 32; o; o >>= 1) v = fmaxf(v, __shfl_xor(v, o));
  return v;
}
__device__ __forceinline__ float wave_sum(float v) {
#pragma unroll
  for (int o = 32; o; o >>= 1) v += __shfl_xor(v, o);
  return v;
}

// One block per batch element. Thread k owns output tag k.
// Linear-domain forward recursion: a <- (ET^T a) * exp(logit_t),
// with exact power-of-2 renorm every 4 steps (esum bookkeeping).
__global__ __launch_bounds__(256, 1)
void crf_fwd(const float* __restrict__ logits,
             const int*   __restrict__ tags,
             const int*   __restrict__ mask,
             const float* __restrict__ trans,
             float* __restrict__ out)
{
  const int b   = blockIdx.x;
  const int k   = threadIdx.x;
  const int wid = k >> 6;

  __shared__ __align__(16) float ebuf[2][NTAGS];  // double-buffered alpha (linear domain)
  __shared__ float red[4];
  __shared__ float rnum[4], rms[4];

  const float LOG2E = 1.4426950408889634f;
  const float LN2   = 0.6931471805599453f;

  const float* lg = logits + (size_t)b * SEQ * NTAGS;
  const int*   tg = tags + b * SEQ;
  const int*   mk = mask + b * SEQ;

  // ---------------- numerator (joint likelihood) ----------------
  float numer = 0.f, msum = 0.f;
  for (int t = k; t < SEQ; t += 256) {
    int   tag_t = tg[t];
    float m_t   = (float)mk[t];
    msum += m_t;
    if (t < SEQ - 1) {
      numer += lg[t * NTAGS + tag_t] * m_t;                       // emit, mask[:, :-1]
      numer += trans[tag_t * NTAGS + tg[t + 1]] * (float)mk[t+1]; // trans, mask[:, 1:]
    }
  }
  numer = wave_sum(numer);
  msum  = wave_sum(msum);
  if ((k & 63) == 0) { rnum[wid] = numer; rms[wid] = msum; }
  __syncthreads();
  const float numer_tot = (rnum[0] + rnum[1]) + (rnum[2] + rnum[3]);
  const float msum_tot  = (rms[0]  + rms[1])  + (rms[2]  + rms[3]);
  __syncthreads();

  // ---------------- ET column k -> registers (f32) ----------------
  // et[j] = exp(trans[j][k]); thread k reads column k (coalesced across lanes).
  float et[NTAGS];
#pragma unroll
  for (int j = 0; j < NTAGS; ++j)
    et[j] = exp2f(trans[j * NTAGS + k] * LOG2E);

  // ---------------- init alpha at t=0 ----------------
  float mya = exp2f(lg[k] * LOG2E);   // exp(logits[b,0,k]); |logit| small, no overflow
  int esum = 0;
  ebuf[0][k] = mya;
  __syncthreads();

  // prefetch logits/mask two steps ahead (only 4 waves/CU -> hide HBM latency)
  float g0 = lg[1 * NTAGS + k];
  float g1 = lg[2 * NTAGS + k];
  int   m0 = mk[1];
  int   m1 = mk[2];

  int cur = 0;
  for (int t = 1; t < SEQ; ++t) {
    const float g = g0;  const int m = m0;
    g0 = g1; m0 = m1;
    const int tpre = (t + 2 <= SEQ - 1) ? (t + 2) : (SEQ - 1);
    g1 = lg[tpre * NTAGS + k];
    m1 = mk[tpre];

    const float4* eb = (const float4*)ebuf[cur];
    float a0 = 0.f, a1 = 0.f, a2 = 0.f, a3 = 0.f;
#pragma unroll
    for (int c = 0; c < NTAGS / 4; ++c) {   // 64 broadcast ds_read_b128 + 256 FMA
      const float4 e4 = eb[c];
      a0 = fmaf(e4.x, et[4 * c + 0], a0);
      a1 = fmaf(e4.y, et[4 * c + 1], a1);
      a2 = fmaf(e4.z, et[4 * c + 2], a2);
      a3 = fmaf(e4.w, et[4 * c + 3], a3);
    }
    const float s = (a0 + a1) + (a2 + a3);
    const float cand = s * exp2f(g * LOG2E);
    mya = m ? cand : mya;   // mask: freeze alpha when mask==0 (block-uniform branch)

    if ((t & 3) == 3) {
      // exact power-of-2 renorm: scale so max ~ [1,2); bookkeep exponent in esum
      float mx = wave_max(mya);
      if ((k & 63) == 0) red[wid] = mx;
      __syncthreads();
      mx = fmaxf(fmaxf(red[0], red[1]), fmaxf(red[2], red[3]));
      __syncthreads();
      const int e = (int)((__float_as_uint(mx) >> 23) & 0xFF) - 127;
      mya *= __uint_as_float((uint32_t)(127 - e) << 23);  // *2^-e, exact
      esum += e;
    }

    cur ^= 1;
    ebuf[cur][k] = mya;
    __syncthreads();
  }

  // ---------------- log_den = log(sum_k a) + esum*ln2 ----------------
  float ssum = wave_sum(mya);
  if ((k & 63) == 0) red[wid] = ssum;
  __syncthreads();
  ssum = (red[0] + red[1]) + (red[2] + red[3]);

  if (k == 0) {
    const float log_den = logf(ssum) + (float)esum * LN2;
    int last_idx = (int)msum_tot - 1;
    if (last_idx < 0) last_idx = 0;
    const int last_tag = tg[last_idx];
    const float score = numer_tot + lg[(SEQ - 1) * NTAGS + last_tag] * (float)mk[SEQ - 1];
    atomicAdd(out, score - log_den);
  }
}

extern "C" void kernel_launch(void* const* d_in, const int* in_sizes, int n_in,
                              void* d_out, int out_size, void* d_ws, size_t ws_size,
                              hipStream_t stream) {
  const float* logits = (const float*)d_in[0];
  const int*   tags   = (const int*)d_in[1];
  const int*   mask   = (const int*)d_in[2];
  const float* trans  = (const float*)d_in[3];
  float* out = (float*)d_out;

  hipMemsetAsync(out, 0, sizeof(float), stream);  // harness poisons d_out with 0xAA
  crf_fwd<<<dim3(BATCH), dim3(256), 0, stream>>>(logits, tags, mask, trans, out);
}

// Round 2
// 658.944 us; speedup vs baseline: 1.4010x; 1.4010x over previous
//
#include <hip/hip_runtime.h>
#include <stdint.h>

#define NTAGS 256
#define BATCH 64
#define SEQ   512

#if __has_builtin(__builtin_amdgcn_fdot2_f32_bf16)
#define HAVE_DOT2_BF16 1
typedef __bf16 bf16x2_t __attribute__((ext_vector_type(2)));
#endif

// ---------------- wave (64-lane) reductions ----------------
__device__ __forceinline__ float wave_max(float v) {
#pragma unroll
  for (int o = 32; o; o >>= 1) v = fmaxf(v, __shfl_xor(v, o));
  return v;
}
__device__ __forceinline__ float wave_sum(float v) {
#pragma unroll
  for (int o = 32; o; o >>= 1) v += __shfl_xor(v, o);
  return v;
}

// f32 -> bf16 bits, round-to-nearest-even (no NaN expected in this data)
__device__ __forceinline__ unsigned int f32_to_bf16_bits(float f) {
  unsigned int u = __float_as_uint(f);
  return (u + 0x7FFFu + ((u >> 16) & 1u)) >> 16;
}

// One block per batch element. Thread k owns output tag k.
// Linear-domain forward recursion: a <- (ET^T a) * exp(logit_t).
// Alpha broadcast via v_readlane -> SGPR (register-file broadcast), NOT via
// uniform-address ds_read (LDS pipe was the round-1 bottleneck: ~3072 cyc/step).
// Alphas + ET held as packed bf16 pairs; v_dot2_f32_bf16 = 2 MAC/instr.
__global__ __launch_bounds__(256, 1)
void crf_fwd(const float* __restrict__ logits,
             const int*   __restrict__ tags,
             const int*   __restrict__ mask,
             const float* __restrict__ trans,
             float* __restrict__ out)
{
  const int b    = blockIdx.x;
  const int k    = threadIdx.x;
  const int wid  = k >> 6;
  const int lane = k & 63;

  __shared__ unsigned int abuf[2][NTAGS / 2];  // alpha, packed bf16x2, double-buffered
  __shared__ float red[4];
  __shared__ float rnum[4], rms[4];

  const float LOG2E = 1.4426950408889634f;
  const float LN2   = 0.6931471805599453f;

  const float* lg = logits + (size_t)b * SEQ * NTAGS;
  const int*   tg = tags + b * SEQ;
  const int*   mk = mask + b * SEQ;

  // ---------------- numerator (joint likelihood) ----------------
  float numer = 0.f, msum = 0.f;
  for (int t = k; t < SEQ; t += 256) {
    int   tag_t = tg[t];
    float m_t   = (float)mk[t];
    msum += m_t;
    if (t < SEQ - 1) {
      numer += lg[t * NTAGS + tag_t] * m_t;                       // emit, mask[:, :-1]
      numer += trans[tag_t * NTAGS + tg[t + 1]] * (float)mk[t+1]; // trans, mask[:, 1:]
    }
  }
  numer = wave_sum(numer);
  msum  = wave_sum(msum);
  if (lane == 0) { rnum[wid] = numer; rms[wid] = msum; }
  __syncthreads();
  const float numer_tot = (rnum[0] + rnum[1]) + (rnum[2] + rnum[3]);
  const float msum_tot  = (rms[0]  + rms[1])  + (rms[2]  + rms[3]);
  __syncthreads();

  // ---------------- ET column k -> registers ----------------
#if HAVE_DOT2_BF16
  // et2[p] = bf16x2( exp(trans[2p][k]), exp(trans[2p+1][k]) ) — 128 VGPRs
  unsigned int et2[NTAGS / 2];
#pragma unroll
  for (int p = 0; p < NTAGS / 2; ++p) {
    float e0 = exp2f(trans[(2 * p)     * NTAGS + k] * LOG2E);
    float e1 = exp2f(trans[(2 * p + 1) * NTAGS + k] * LOG2E);
    et2[p] = f32_to_bf16_bits(e0) | (f32_to_bf16_bits(e1) << 16);
  }
#else
  float et[NTAGS];
#pragma unroll
  for (int j = 0; j < NTAGS; ++j)
    et[j] = exp2f(trans[j * NTAGS + k] * LOG2E);
#endif

  // ---------------- init alpha at t=0 ----------------
  float mya = exp2f(lg[k] * LOG2E);
  int esum = 0;
  ((unsigned short*)abuf[0])[k] = (unsigned short)f32_to_bf16_bits(mya);
  __syncthreads();

  // prefetch logits/mask two steps ahead
  float g0 = lg[1 * NTAGS + k];
  float g1 = lg[2 * NTAGS + k];
  int   m0v = mk[1];
  int   m1v = mk[2];

  int cur = 0;
  for (int t = 1; t < SEQ; ++t) {
    const float g = g0;  const int m = m0v;
    g0 = g1; m0v = m1v;
    const int tpre = (t + 2 <= SEQ - 1) ? (t + 2) : (SEQ - 1);
    g1 = lg[tpre * NTAGS + k];
    m1v = mk[tpre];

    // each lane loads 2 packed-bf16 alpha words (stride-1 u32: 2-way aliasing, free)
    const int w0 = (int)abuf[cur][lane];
    const int w1 = (int)abuf[cur][64 + lane];

    float acc[4] = {0.f, 0.f, 0.f, 0.f};  // 4 chains to cover dot/fma latency
#if HAVE_DOT2_BF16
#pragma unroll
    for (int p = 0; p < 64; ++p) {
      int s01 = __builtin_amdgcn_readlane(w0, p);              // SGPR broadcast
      acc[p & 3] = __builtin_amdgcn_fdot2_f32_bf16(
          __builtin_bit_cast(bf16x2_t, et2[p]),
          __builtin_bit_cast(bf16x2_t, s01), acc[p & 3], false);
    }
#pragma unroll
    for (int p = 0; p < 64; ++p) {
      int s01 = __builtin_amdgcn_readlane(w1, p);
      acc[p & 3] = __builtin_amdgcn_fdot2_f32_bf16(
          __builtin_bit_cast(bf16x2_t, et2[64 + p]),
          __builtin_bit_cast(bf16x2_t, s01), acc[p & 3], false);
    }
#else
#pragma unroll
    for (int p = 0; p < 64; ++p) {
      int s01 = __builtin_amdgcn_readlane(w0, p);
      float alo = __uint_as_float(((unsigned int)s01) << 16);         // scalar ALU
      float ahi = __uint_as_float(((unsigned int)s01) & 0xFFFF0000u); // scalar ALU
      acc[p & 3] = fmaf(alo, et[2 * p], acc[p & 3]);
      acc[p & 3] = fmaf(ahi, et[2 * p + 1], acc[p & 3]);
    }
#pragma unroll
    for (int p = 0; p < 64; ++p) {
      int s01 = __builtin_amdgcn_readlane(w1, p);
      float alo = __uint_as_float(((unsigned int)s01) << 16);
      float ahi = __uint_as_float(((unsigned int)s01) & 0xFFFF0000u);
      acc[p & 3] = fmaf(alo, et[128 + 2 * p], acc[p & 3]);
      acc[p & 3] = fmaf(ahi, et[128 + 2 * p + 1], acc[p & 3]);
    }
#endif
    const float s = (acc[0] + acc[1]) + (acc[2] + acc[3]);
    const float cand = s * exp2f(g * LOG2E);
    mya = m ? cand : mya;   // mask: freeze alpha when mask==0 (block-uniform)

    if ((t & 3) == 3) {
      // exact power-of-2 renorm every 4 steps; exponent bookkeeping in esum
      float mx = wave_max(mya);
      if (lane == 0) red[wid] = mx;
      __syncthreads();
      mx = fmaxf(fmaxf(red[0], red[1]), fmaxf(red[2], red[3]));
      __syncthreads();
      const int e = (int)((__float_as_uint(mx) >> 23) & 0xFF) - 127;
      mya *= __uint_as_float((uint32_t)(127 - e) << 23);  // *2^-e, exact
      esum += e;
    }

    cur ^= 1;
    ((unsigned short*)abuf[cur])[k] = (unsigned short)f32_to_bf16_bits(mya);
    __syncthreads();
  }

  // ---------------- log_den = log(sum_k a) + esum*ln2 ----------------
  float ssum = wave_sum(mya);
  if (lane == 0) red[wid] = ssum;
  __syncthreads();
  ssum = (red[0] + red[1]) + (red[2] + red[3]);

  if (k == 0) {
    const float log_den = logf(ssum) + (float)esum * LN2;
    int last_idx = (int)msum_tot - 1;
    if (last_idx < 0) last_idx = 0;
    const int last_tag = tg[last_idx];
    const float score = numer_tot + lg[(SEQ - 1) * NTAGS + last_tag] * (float)mk[SEQ - 1];
    atomicAdd(out, score - log_den);
  }
}

extern "C" void kernel_launch(void* const* d_in, const int* in_sizes, int n_in,
                              void* d_out, int out_size, void* d_ws, size_t ws_size,
                              hipStream_t stream) {
  const float* logits = (const float*)d_in[0];
  const int*   tags   = (const int*)d_in[1];
  const int*   mask   = (const int*)d_in[2];
  const float* trans  = (const float*)d_in[3];
  float* out = (float*)d_out;

  hipMemsetAsync(out, 0, sizeof(float), stream);  // harness poisons d_out with 0xAA
  crf_fwd<<<dim3(BATCH), dim3(256), 0, stream>>>(logits, tags, mask, trans, out);
}

// Round 3
// 656.423 us; speedup vs baseline: 1.4064x; 1.0038x over previous
//
#include <hip/hip_runtime.h>
#include <stdint.h>

#define NTAGS 256
#define BATCH 64
#define SEQ   512

#if __has_builtin(__builtin_amdgcn_fdot2_f32_bf16)
#define HAVE_DOT2_BF16 1
typedef __bf16 bf16x2_t __attribute__((ext_vector_type(2)));
#define BCAST(x) __builtin_bit_cast(bf16x2_t, (unsigned int)(x))
#endif

// ---------------- wave (64-lane) reductions ----------------
__device__ __forceinline__ float wave_max(float v) {
#pragma unroll
  for (int o = 32; o; o >>= 1) v = fmaxf(v, __shfl_xor(v, o));
  return v;
}
__device__ __forceinline__ float wave_sum(float v) {
#pragma unroll
  for (int o = 32; o; o >>= 1) v += __shfl_xor(v, o);
  return v;
}

// f32 -> bf16 bits, round-to-nearest-even
__device__ __forceinline__ unsigned int f32_to_bf16_bits(float f) {
  unsigned int u = __float_as_uint(f);
  return (u + 0x7FFFu + ((u >> 16) & 1u)) >> 16;
}

// 128 ET registers as NAMED locals: regalloc cannot demote named scalars to a
// scratch array (rounds 1-2 both silently spilled their et[] arrays -> the
// per-step scratch reloads were the real bottleneck, VGPR_Count 84 proved it).
#define ET_ALL(M) \
  M(0) M(1) M(2) M(3) M(4) M(5) M(6) M(7) \
  M(8) M(9) M(10) M(11) M(12) M(13) M(14) M(15) \
  M(16) M(17) M(18) M(19) M(20) M(21) M(22) M(23) \
  M(24) M(25) M(26) M(27) M(28) M(29) M(30) M(31) \
  M(32) M(33) M(34) M(35) M(36) M(37) M(38) M(39) \
  M(40) M(41) M(42) M(43) M(44) M(45) M(46) M(47) \
  M(48) M(49) M(50) M(51) M(52) M(53) M(54) M(55) \
  M(56) M(57) M(58) M(59) M(60) M(61) M(62) M(63) \
  M(64) M(65) M(66) M(67) M(68) M(69) M(70) M(71) \
  M(72) M(73) M(74) M(75) M(76) M(77) M(78) M(79) \
  M(80) M(81) M(82) M(83) M(84) M(85) M(86) M(87) \
  M(88) M(89) M(90) M(91) M(92) M(93) M(94) M(95) \
  M(96) M(97) M(98) M(99) M(100) M(101) M(102) M(103) \
  M(104) M(105) M(106) M(107) M(108) M(109) M(110) M(111) \
  M(112) M(113) M(114) M(115) M(116) M(117) M(118) M(119) \
  M(120) M(121) M(122) M(123) M(124) M(125) M(126) M(127)

// 64 lines; (i, j=i+64, chain_a, chain_b). 8 acc chains -> dependent reuse of a
// chain is >= 8 instructions apart (covers ~4-cyc VALU dependency latency).
#define DOT_ALL(M) \
  M(0,64,0,1) M(1,65,2,3) M(2,66,4,5) M(3,67,6,7) \
  M(4,68,0,1) M(5,69,2,3) M(6,70,4,5) M(7,71,6,7) \
  M(8,72,0,1) M(9,73,2,3) M(10,74,4,5) M(11,75,6,7) \
  M(12,76,0,1) M(13,77,2,3) M(14,78,4,5) M(15,79,6,7) \
  M(16,80,0,1) M(17,81,2,3) M(18,82,4,5) M(19,83,6,7) \
  M(20,84,0,1) M(21,85,2,3) M(22,86,4,5) M(23,87,6,7) \
  M(24,88,0,1) M(25,89,2,3) M(26,90,4,5) M(27,91,6,7) \
  M(28,92,0,1) M(29,93,2,3) M(30,94,4,5) M(31,95,6,7) \
  M(32,96,0,1) M(33,97,2,3) M(34,98,4,5) M(35,99,6,7) \
  M(36,100,0,1) M(37,101,2,3) M(38,102,4,5) M(39,103,6,7) \
  M(40,104,0,1) M(41,105,2,3) M(42,106,4,5) M(43,107,6,7) \
  M(44,108,0,1) M(45,109,2,3) M(46,110,4,5) M(47,111,6,7) \
  M(48,112,0,1) M(49,113,2,3) M(50,114,4,5) M(51,115,6,7) \
  M(52,116,0,1) M(53,117,2,3) M(54,118,4,5) M(55,119,6,7) \
  M(56,120,0,1) M(57,121,2,3) M(58,122,4,5) M(59,123,6,7) \
  M(60,124,0,1) M(61,125,2,3) M(62,126,4,5) M(63,127,6,7)

#define ET_DECL(i) unsigned int et##i;
#define ET_INIT(i) \
  et##i = f32_to_bf16_bits(exp2f(trans[(2*(i))*NTAGS + k] * LOG2E)) | \
          (f32_to_bf16_bits(exp2f(trans[(2*(i)+1)*NTAGS + k] * LOG2E)) << 16);

#if HAVE_DOT2_BF16
#define DOT_STEP(i, j, ca, cb) { \
    int sa_ = __builtin_amdgcn_readlane(w0, i); \
    acc##ca = __builtin_amdgcn_fdot2_f32_bf16(BCAST(et##i), BCAST(sa_), acc##ca, false); \
    int sb_ = __builtin_amdgcn_readlane(w1, i); \
    acc##cb = __builtin_amdgcn_fdot2_f32_bf16(BCAST(et##j), BCAST(sb_), acc##cb, false); }
#else
#define DOT_STEP(i, j, ca, cb) { \
    unsigned int sa_ = (unsigned int)__builtin_amdgcn_readlane(w0, i); \
    acc##ca = fmaf(__uint_as_float(sa_ << 16),        __uint_as_float(et##i << 16),        acc##ca); \
    acc##cb = fmaf(__uint_as_float(sa_ & 0xFFFF0000u), __uint_as_float(et##i & 0xFFFF0000u), acc##cb); \
    unsigned int sb_ = (unsigned int)__builtin_amdgcn_readlane(w1, i); \
    acc##ca = fmaf(__uint_as_float(sb_ << 16),        __uint_as_float(et##j << 16),        acc##ca); \
    acc##cb = fmaf(__uint_as_float(sb_ & 0xFFFF0000u), __uint_as_float(et##j & 0xFFFF0000u), acc##cb); }
#endif

// One block per batch element. Thread k owns output tag k.
// Linear-domain forward recursion: a <- (ET^T a) * exp(logit_t), alpha
// broadcast lane->SGPR via v_readlane, exact power-of-2 renorm every 4 steps.
__global__ __launch_bounds__(256, 1)
void crf_fwd(const float* __restrict__ logits,
             const int*   __restrict__ tags,
             const int*   __restrict__ mask,
             const float* __restrict__ trans,
             float* __restrict__ out)
{
  const int b    = blockIdx.x;
  const int k    = threadIdx.x;
  const int wid  = k >> 6;
  const int lane = k & 63;

  __shared__ unsigned int abuf[2][NTAGS / 2];  // alpha, packed bf16x2, double-buffered
  __shared__ float red[4];
  __shared__ float rnum[4], rms[4];

  const float LOG2E = 1.4426950408889634f;
  const float LN2   = 0.6931471805599453f;

  const float* lg = logits + (size_t)b * SEQ * NTAGS;
  const int*   tg = tags + b * SEQ;
  const int*   mk = mask + b * SEQ;

  // ---------------- numerator (joint likelihood) ----------------
  float numer = 0.f, msum = 0.f;
  for (int t = k; t < SEQ; t += 256) {
    int   tag_t = tg[t];
    float m_t   = (float)mk[t];
    msum += m_t;
    if (t < SEQ - 1) {
      numer += lg[t * NTAGS + tag_t] * m_t;                       // emit, mask[:, :-1]
      numer += trans[tag_t * NTAGS + tg[t + 1]] * (float)mk[t+1]; // trans, mask[:, 1:]
    }
  }
  numer = wave_sum(numer);
  msum  = wave_sum(msum);
  if (lane == 0) { rnum[wid] = numer; rms[wid] = msum; }
  __syncthreads();
  const float numer_tot = (rnum[0] + rnum[1]) + (rnum[2] + rnum[3]);
  const float msum_tot  = (rms[0]  + rms[1])  + (rms[2]  + rms[3]);
  __syncthreads();

  // ---------------- ET column k -> 128 named registers ----------------
  ET_ALL(ET_DECL)
  ET_ALL(ET_INIT)

  // ---------------- init alpha at t=0 ----------------
  float mya = exp2f(lg[k] * LOG2E);
  int esum = 0;
  ((unsigned short*)abuf[0])[k] = (unsigned short)f32_to_bf16_bits(mya);
  __syncthreads();

  // prefetch logits/mask two steps ahead
  float g0 = lg[1 * NTAGS + k];
  float g1 = lg[2 * NTAGS + k];
  int   m0v = mk[1];
  int   m1v = mk[2];

  int cur = 0;
  for (int t = 1; t < SEQ; ++t) {
    const float g = g0;  const int m = m0v;
    g0 = g1; m0v = m1v;
    const int tpre = (t + 2 <= SEQ - 1) ? (t + 2) : (SEQ - 1);
    g1 = lg[tpre * NTAGS + k];
    m1v = mk[tpre];

    // each lane loads 2 packed-bf16 alpha words (stride-1 u32, conflict-free)
    const int w0 = (int)abuf[cur][lane];
    const int w1 = (int)abuf[cur][64 + lane];

    float acc0 = 0.f, acc1 = 0.f, acc2 = 0.f, acc3 = 0.f;
    float acc4 = 0.f, acc5 = 0.f, acc6 = 0.f, acc7 = 0.f;
    DOT_ALL(DOT_STEP)

    const float s = ((acc0 + acc1) + (acc2 + acc3)) + ((acc4 + acc5) + (acc6 + acc7));
    const float cand = s * exp2f(g * LOG2E);
    mya = m ? cand : mya;   // mask: freeze alpha when mask==0 (block-uniform)

    if ((t & 3) == 3) {
      // exact power-of-2 renorm every 4 steps; exponent bookkeeping in esum
      float mx = wave_max(mya);
      if (lane == 0) red[wid] = mx;
      __syncthreads();
      mx = fmaxf(fmaxf(red[0], red[1]), fmaxf(red[2], red[3]));
      const int e = (int)((__float_as_uint(mx) >> 23) & 0xFF) - 127;
      mya *= __uint_as_float((uint32_t)(127 - e) << 23);  // *2^-e, exact
      esum += e;
    }

    cur ^= 1;
    ((unsigned short*)abuf[cur])[k] = (unsigned short)f32_to_bf16_bits(mya);
    __syncthreads();
  }

  // ---------------- log_den = log(sum_k a) + esum*ln2 ----------------
  float ssum = wave_sum(mya);
  if (lane == 0) red[wid] = ssum;
  __syncthreads();
  ssum = (red[0] + red[1]) + (red[2] + red[3]);

  if (k == 0) {
    const float log_den = logf(ssum) + (float)esum * LN2;
    int last_idx = (int)msum_tot - 1;
    if (last_idx < 0) last_idx = 0;
    const int last_tag = tg[last_idx];
    const float score = numer_tot + lg[(SEQ - 1) * NTAGS + last_tag] * (float)mk[SEQ - 1];
    atomicAdd(out, score - log_den);
  }
}

extern "C" void kernel_launch(void* const* d_in, const int* in_sizes, int n_in,
                              void* d_out, int out_size, void* d_ws, size_t ws_size,
                              hipStream_t stream) {
  const float* logits = (const float*)d_in[0];
  const int*   tags   = (const int*)d_in[1];
  const int*   mask   = (const int*)d_in[2];
  const float* trans  = (const float*)d_in[3];
  float* out = (float*)d_out;

  hipMemsetAsync(out, 0, sizeof(float), stream);  // harness poisons d_out with 0xAA
  crf_fwd<<<dim3(BATCH), dim3(256), 0, stream>>>(logits, tags, mask, trans, out);
}